// Round 1
// 2892.232 us; speedup vs baseline: 1.0334x; 1.0334x over previous
//
#include <hip/hip_runtime.h>
#include <stdint.h>

typedef short short8 __attribute__((ext_vector_type(8)));
typedef float floatx4 __attribute__((ext_vector_type(4)));

__device__ __forceinline__ float bf2f(unsigned short u) {
    union { unsigned int u; float f; } c; c.u = ((unsigned int)u) << 16; return c.f;
}
__device__ __forceinline__ unsigned short f2bf(float f) {
    union { float f; unsigned int u; } c; c.f = f;
    unsigned int u = c.u;
    unsigned int r = (u + 0x7fffu + ((u >> 16) & 1u)) >> 16;
    return (unsigned short)r;
}

// async global->LDS, 16B per lane; LDS dest is wave-uniform base + lane*16
__device__ __forceinline__ void gload16(const unsigned short* g, unsigned short* l) {
    __builtin_amdgcn_global_load_lds(
        (const __attribute__((address_space(1))) unsigned int*)g,
        (__attribute__((address_space(3))) unsigned int*)l,
        16, 0, 0);
}

// ---------------- zero ints (replaces hipMemsetAsync) ----------------
__global__ __launch_bounds__(256) void k_zero(int* __restrict__ p, int n) {
    int i = blockIdx.x * 256 + threadIdx.x;
    int stride = gridDim.x * 256;
    for (; i < n; i += stride) p[i] = 0;
}

// ---------------- convert fp32 -> bf16 (vectorized) ----------------
__global__ __launch_bounds__(256) void k_cvt_x(const float* __restrict__ x,
                                               unsigned short* __restrict__ xb,
                                               long long n4) {
    long long i = (long long)blockIdx.x * blockDim.x + threadIdx.x;
    long long stride = (long long)gridDim.x * blockDim.x;
    for (; i < n4; i += stride) {
        float4 v = ((const float4*)x)[i];
        ushort4 o;
        o.x = f2bf(v.x); o.y = f2bf(v.y); o.z = f2bf(v.z); o.w = f2bf(v.w);
        ((ushort4*)xb)[i] = o;
    }
}

// ---------------- transpose W (fp32 [K][N]) -> Wt bf16 [N][K] ----------------
__global__ __launch_bounds__(256) void k_twt(const float* __restrict__ W,
                                             unsigned short* __restrict__ Wt) {
    __shared__ float tile[32][33];
    int bn = blockIdx.x * 32;  // n block
    int bk = blockIdx.y * 32;  // k block
    int tx = threadIdx.x;      // 0..31
    int ty = threadIdx.y;      // 0..7
    for (int i = ty; i < 32; i += 8)
        tile[i][tx] = W[(size_t)(bk + i) * 768 + bn + tx];
    __syncthreads();
    for (int i = ty; i < 32; i += 8)
        Wt[(size_t)(bn + i) * 768 + bk + tx] = f2bf(tile[tx][i]);
}

// ---------------- per-relation unweighted degrees ----------------
__global__ __launch_bounds__(256) void k_deg(const int* __restrict__ s, const int* __restrict__ d,
                                             int* od, int* id, int ne) {
    int e = blockIdx.x * 256 + threadIdx.x;
    if (e < ne) { atomicAdd(&od[s[e]], 1); atomicAdd(&id[d[e]], 1); }
}

// ---------------- combined counts + scan-free segment starts ----------------
__global__ __launch_bounds__(256) void k_cnt(const int* __restrict__ id1, const int* __restrict__ id2,
                                             const int* __restrict__ id3,
                                             int* __restrict__ cnt, int* __restrict__ start,
                                             int* __restrict__ cur, int* cursor, int n) {
    int i = blockIdx.x * 256 + threadIdx.x;
    int c = 0;
    if (i < n) {
        c = id1[i] + id2[i] + id3[i];
        cnt[i] = c;
        cur[i] = 0;
    }
    // wave-level inclusive scan -> one atomic per wave (segment order is irrelevant)
    int lane = threadIdx.x & 63;
    int v = c;
    #pragma unroll
    for (int off = 1; off < 64; off <<= 1) {
        int u = __shfl_up(v, off, 64);
        if (lane >= off) v += u;
    }
    int total = __shfl(v, 63, 64);
    int base = 0;
    if (lane == 63) base = atomicAdd(cursor, total);
    base = __shfl(base, 63, 64);
    if (i < n) start[i] = base + v - c;
}

// ---------------- bucket edges by dst: store (zrow, coef) ----------------
__global__ __launch_bounds__(256) void k_fill(const int* __restrict__ src, const int* __restrict__ dst,
                                              const float* __restrict__ w,
                                              const int* __restrict__ od, const int* __restrict__ id,
                                              const int* __restrict__ start, int* cur,
                                              int2* __restrict__ e2, int soff, int ne) {
    int e = blockIdx.x * 256 + threadIdx.x;
    if (e >= ne) return;
    int s = src[e], d = dst[e];
    int pos = start[d] + atomicAdd(&cur[d], 1);
    int odv = od[s]; if (odv < 1) odv = 1;
    int idv = id[d]; if (idv < 1) idv = 1;
    float c = w[e] * rsqrtf((float)odv) * rsqrtf((float)idv);
    int2 rec; rec.x = soff + s; rec.y = __float_as_int(c);
    e2[pos] = rec;
}

// ---------------- 128x128 bf16 MFMA GEMM, m97 structure ----------------
// Z = Xb @ W  (Wt is [N][K] bf16).  global_load_lds width-16 staging into
// linear LDS [128][32]; single-buffered, 2 barriers per K-step.
__global__ __launch_bounds__(256) void k_gemm(const unsigned short* __restrict__ A,
                                              const unsigned short* __restrict__ Bt,
                                              unsigned short* __restrict__ C,
                                              int Mrows) {
    __shared__ __align__(16) unsigned short As[128 * 32];
    __shared__ __align__(16) unsigned short Bs[128 * 32];
    const int tid = threadIdx.x;
    const int m0 = blockIdx.x * 128;
    const int n0 = blockIdx.y * 128;
    const int lane = tid & 63;
    const int wave = tid >> 6;
    const int wm = (wave >> 1) * 64;
    const int wn = (wave & 1) * 64;
    const int l16 = lane & 15;
    const int quad = lane >> 4;

    floatx4 acc[4][4];
    #pragma unroll
    for (int i = 0; i < 4; i++)
        #pragma unroll
        for (int j = 0; j < 4; j++) acc[i][j] = (floatx4){0.f, 0.f, 0.f, 0.f};

    // staging: linear chunk index l = tid + 256*j covers LDS bytes [l*16, l*16+16)
    // row = l/4 (32 bf16 = 64B per row), chunk col = l%4 -> bf16 col (l%4)*8
    const int l0 = tid;
    const int l1 = tid + 256;
    const int r0 = l0 >> 2, c0 = (l0 & 3) * 8;
    const int r1 = l1 >> 2, c1 = (l1 & 3) * 8;
    int ar0 = m0 + r0; if (ar0 >= Mrows) ar0 = Mrows - 1;   // clamp: garbage masked at store
    int ar1 = m0 + r1; if (ar1 >= Mrows) ar1 = Mrows - 1;
    const unsigned short* Ag0 = A + (size_t)ar0 * 768 + c0;
    const unsigned short* Ag1 = A + (size_t)ar1 * 768 + c1;
    const unsigned short* Bg0 = Bt + (size_t)(n0 + r0) * 768 + c0;   // n0+r < 768 always
    const unsigned short* Bg1 = Bt + (size_t)(n0 + r1) * 768 + c1;
    // per-wave uniform LDS bases (ushort units): inst j base = wave*512 + j*2048
    unsigned short* Al0 = As + wave * 512;
    unsigned short* Al1 = As + wave * 512 + 2048;
    unsigned short* Bl0 = Bs + wave * 512;
    unsigned short* Bl1 = Bs + wave * 512 + 2048;

    for (int k0 = 0; k0 < 768; k0 += 32) {
        __syncthreads();               // previous iteration's fragment reads done
        gload16(Ag0 + k0, Al0);
        gload16(Ag1 + k0, Al1);
        gload16(Bg0 + k0, Bl0);
        gload16(Bg1 + k0, Bl1);
        asm volatile("s_waitcnt vmcnt(0)" ::: "memory");
        __syncthreads();               // tile visible to all waves

        short8 af[4], bfr[4];
        #pragma unroll
        for (int mt = 0; mt < 4; mt++)
            af[mt] = *(const short8*)&As[(wm + mt * 16 + l16) * 32 + quad * 8];
        #pragma unroll
        for (int nt = 0; nt < 4; nt++)
            bfr[nt] = *(const short8*)&Bs[(wn + nt * 16 + l16) * 32 + quad * 8];
        #pragma unroll
        for (int mt = 0; mt < 4; mt++)
            #pragma unroll
            for (int nt = 0; nt < 4; nt++)
                acc[mt][nt] = __builtin_amdgcn_mfma_f32_16x16x32_bf16(af[mt], bfr[nt], acc[mt][nt], 0, 0, 0);
    }

    #pragma unroll
    for (int mt = 0; mt < 4; mt++) {
        #pragma unroll
        for (int nt = 0; nt < 4; nt++) {
            const int gr0 = m0 + wm + mt * 16 + quad * 4;
            const int gc = n0 + wn + nt * 16 + l16;
            #pragma unroll
            for (int r = 0; r < 4; r++) {
                int gr = gr0 + r;
                if (gr < Mrows)
                    C[(size_t)gr * 768 + gc] = f2bf(acc[mt][nt][r]);
            }
        }
    }
}

// ---------------- dst-centric aggregation + bias + ReLU ----------------
__global__ __launch_bounds__(192) void k_agg(const unsigned short* __restrict__ Z,
                                             const int* __restrict__ start, const int* __restrict__ cnt,
                                             const int2* __restrict__ e2,
                                             const float* __restrict__ b1, const float* __restrict__ b2,
                                             const float* __restrict__ b3,
                                             float* __restrict__ out, int n) {
    int node = blockIdx.x;
    if (node >= n) return;
    int t = threadIdx.x;       // 0..191, owns 4 consecutive cols
    int c0 = t * 4;
    int s = start[node];
    int e = s + cnt[node];
    float ax = 0.f, ay = 0.f, az = 0.f, aw = 0.f;
    for (int i = s; i < e; i++) {
        int2 ed = e2[i];
        float c = __int_as_float(ed.y);
        ushort4 v = *(const ushort4*)(Z + (size_t)ed.x * 768 + c0);
        ax += c * bf2f(v.x);
        ay += c * bf2f(v.y);
        az += c * bf2f(v.z);
        aw += c * bf2f(v.w);
    }
    float4 o;
    o.x = ax + b1[c0 + 0] + b2[c0 + 0] + b3[c0 + 0];
    o.y = ay + b1[c0 + 1] + b2[c0 + 1] + b3[c0 + 1];
    o.z = az + b1[c0 + 2] + b2[c0 + 2] + b3[c0 + 2];
    o.w = aw + b1[c0 + 3] + b2[c0 + 3] + b3[c0 + 3];
    o.x = fmaxf(o.x, 0.f); o.y = fmaxf(o.y, 0.f);
    o.z = fmaxf(o.z, 0.f); o.w = fmaxf(o.w, 0.f);
    *(float4*)(out + (size_t)node * 768 + c0) = o;
}

extern "C" void kernel_launch(void* const* d_in, const int* in_sizes, int n_in,
                              void* d_out, int out_size, void* d_ws, size_t ws_size,
                              hipStream_t stream) {
    const int NM = 100000, NE = 40000, NS = 20000;
    const int EREL = 250000;
    (void)in_sizes; (void)n_in; (void)out_size;

    const float* xM = (const float*)d_in[0];
    const float* xE = (const float*)d_in[1];
    const float* xS = (const float*)d_in[2];
    const int* src[9]; const int* dst[9];
    const float* w[9]; const float* W[9]; const float* b[9];
    for (int r = 0; r < 9; r++) {
        src[r] = (const int*)d_in[3 + 5 * r + 0];
        dst[r] = (const int*)d_in[3 + 5 * r + 1];
        w[r]   = (const float*)d_in[3 + 5 * r + 2];
        W[r]   = (const float*)d_in[3 + 5 * r + 3];
        b[r]   = (const float*)d_in[3 + 5 * r + 4];
    }

    // workspace layout (bytes)
    const size_t XB_OFF = 0;                      // 160000*768 bf16
    const size_t Z_OFF  = 245760000;              // 160000*768 bf16
    const size_t WT_OFF = 491520000;              // 9*768*768 bf16 -> end 502,136,832
    const size_t OD_OFF = 502136832;              // 9*100000 int
    const size_t ID_OFF = 505736832;              // 9*100000 int
    const size_t CURSOR_OFF = 509336832;          // 64 ints (3 used)
    const size_t CNT_OFF = 509337088;             // 100000 int
    const size_t START_OFF = 509737088;           // 100000 int
    const size_t CUR_OFF = 510137088;             // 100000 int
    const size_t E2_OFF = 510537088;              // 750000 int2
    const size_t WS_NEEDED = 516537088;
    if (ws_size < WS_NEEDED) return;  // workspace too small -> fails visibly at validation

    char* ws = (char*)d_ws;
    unsigned short* Xb = (unsigned short*)(ws + XB_OFF);
    unsigned short* Z  = (unsigned short*)(ws + Z_OFF);
    unsigned short* Wt = (unsigned short*)(ws + WT_OFF);
    int* od     = (int*)(ws + OD_OFF);
    int* id     = (int*)(ws + ID_OFF);
    int* cursor = (int*)(ws + CURSOR_OFF);
    int* cnt    = (int*)(ws + CNT_OFF);
    int* start  = (int*)(ws + START_OFF);
    int* cur    = (int*)(ws + CUR_OFF);
    int2* e2    = (int2*)(ws + E2_OFF);

    // relation metadata: RELS = M_M,M_E,M_S,E_S,E_M,S_M,S_E,S_S,E_E
    const int rel_soff[9] = {0, 0, 0, 100000, 100000, 140000, 140000, 140000, 100000};
    const int rel_nsrc[9] = {NM, NM, NM, NE, NE, NS, NS, NS, NE};
    const int phase_nd[3]  = {NM, NE, NS};
    const int phase_out[3] = {0, 100000, 140000};
    const int phase_rels[3][3] = { {0, 4, 5}, {1, 8, 6}, {2, 3, 7} };  // dst M / E / S

    // zero od+id+cursor block: (502,136,832 .. 509,337,088) = 1,800,064 ints
    k_zero<<<1760, 256, 0, stream>>>(od, 1800064);

    const int eblk = (EREL + 255) / 256;
    for (int r = 0; r < 9; r++)
        k_deg<<<eblk, 256, 0, stream>>>(src[r], dst[r], od + r * 100000, id + r * 100000, EREL);

    k_cvt_x<<<4096, 256, 0, stream>>>(xM, Xb, (long long)NM * 768 / 4);
    k_cvt_x<<<2048, 256, 0, stream>>>(xE, Xb + (size_t)100000 * 768, (long long)NE * 768 / 4);
    k_cvt_x<<<1024, 256, 0, stream>>>(xS, Xb + (size_t)140000 * 768, (long long)NS * 768 / 4);

    for (int r = 0; r < 9; r++)
        k_twt<<<dim3(24, 24), dim3(32, 8), 0, stream>>>(W[r], Wt + (size_t)r * 589824);

    for (int p = 0; p < 3; p++) {
        const int nd = phase_nd[p];
        const int r0 = phase_rels[p][0], r1 = phase_rels[p][1], r2 = phase_rels[p][2];

        // 3 GEMMs into the shared Z buffer (row ranges by src type)
        for (int j = 0; j < 3; j++) {
            int r = phase_rels[p][j];
            dim3 g((rel_nsrc[r] + 127) / 128, 6);
            k_gemm<<<g, 256, 0, stream>>>(Xb + (size_t)rel_soff[r] * 768,
                                          Wt + (size_t)r * 589824,
                                          Z + (size_t)rel_soff[r] * 768,
                                          rel_nsrc[r]);
        }

        k_cnt<<<(nd + 255) / 256, 256, 0, stream>>>(id + r0 * 100000, id + r1 * 100000,
                                                    id + r2 * 100000, cnt, start, cur, cursor + p, nd);
        for (int j = 0; j < 3; j++) {
            int r = phase_rels[p][j];
            k_fill<<<eblk, 256, 0, stream>>>(src[r], dst[r], w[r],
                                             od + r * 100000, id + r * 100000,
                                             start, cur, e2, rel_soff[r], EREL);
        }
        k_agg<<<nd, 192, 0, stream>>>(Z, start, cnt, e2, b[r0], b[r1], b[r2],
                                      (float*)d_out + (size_t)phase_out[p] * 768, nd);
    }
}

// Round 2
// 2643.023 us; speedup vs baseline: 1.1309x; 1.0943x over previous
//
#include <hip/hip_runtime.h>
#include <stdint.h>

typedef short short8 __attribute__((ext_vector_type(8)));
typedef float floatx4 __attribute__((ext_vector_type(4)));

__device__ __forceinline__ float bf2f(unsigned short u) {
    union { unsigned int u; float f; } c; c.u = ((unsigned int)u) << 16; return c.f;
}
__device__ __forceinline__ unsigned short f2bf(float f) {
    union { float f; unsigned int u; } c; c.f = f;
    unsigned int u = c.u;
    unsigned int r = (u + 0x7fffu + ((u >> 16) & 1u)) >> 16;
    return (unsigned short)r;
}

// async global->LDS, 16B per lane; LDS dest is wave-uniform base + lane*16
__device__ __forceinline__ void gload16(const unsigned short* g, unsigned short* l) {
    __builtin_amdgcn_global_load_lds(
        (const __attribute__((address_space(1))) unsigned int*)g,
        (__attribute__((address_space(3))) unsigned int*)l,
        16, 0, 0);
}

struct DegArgs { const int* s[9]; const int* d[9]; };
struct TwtArgs { const float* W[9]; int slot[9]; };
struct CvtArgs { const float* xM; const float* xE; const float* xS; };
struct FillArgs {
    const int* src[3]; const int* dst[3]; const float* w[3];
    const int* od[3]; const int* id[3]; int soff[3];
};

// ---------------- zero ints ----------------
__global__ __launch_bounds__(256) void k_zero(int* __restrict__ p, int n) {
    int i = blockIdx.x * 256 + threadIdx.x;
    int stride = gridDim.x * 256;
    for (; i < n; i += stride) p[i] = 0;
}

// ---------------- fp32 -> bf16, all 3 inputs in one launch ----------------
__global__ __launch_bounds__(256) void k_cvt_all(CvtArgs P, unsigned short* __restrict__ xb) {
    const long long NM4 = 19200000LL;   // 100000*192
    const long long NE4 = 26880000LL;   // +40000*192
    const long long NT4 = 30720000LL;   // +20000*192
    long long i = (long long)blockIdx.x * blockDim.x + threadIdx.x;
    long long stride = (long long)gridDim.x * blockDim.x;
    for (; i < NT4; i += stride) {
        float4 v;
        if (i < NM4)       v = ((const float4*)P.xM)[i];
        else if (i < NE4)  v = ((const float4*)P.xE)[i - NM4];
        else               v = ((const float4*)P.xS)[i - NE4];
        ushort4 o;
        o.x = f2bf(v.x); o.y = f2bf(v.y); o.z = f2bf(v.z); o.w = f2bf(v.w);
        ((ushort4*)xb)[i] = o;
    }
}

// ---------------- transpose all 9 W (fp32 [K][N]) -> Wt bf16 [N][K], slot-ordered ----------------
__global__ __launch_bounds__(256) void k_twt_all(TwtArgs P, unsigned short* __restrict__ WtBase) {
    __shared__ float tile[32][33];
    int r = blockIdx.z;
    const float* W = P.W[r];
    unsigned short* Wt = WtBase + (size_t)P.slot[r] * 589824;
    int bn = blockIdx.x * 32;
    int bk = blockIdx.y * 32;
    int tx = threadIdx.x;      // 0..31
    int ty = threadIdx.y;      // 0..7
    for (int i = ty; i < 32; i += 8)
        tile[i][tx] = W[(size_t)(bk + i) * 768 + bn + tx];
    __syncthreads();
    for (int i = ty; i < 32; i += 8)
        Wt[(size_t)(bn + i) * 768 + bk + tx] = f2bf(tile[tx][i]);
}

// ---------------- per-relation unweighted degrees, all 9 relations ----------------
__global__ __launch_bounds__(256) void k_deg_all(DegArgs P, int* __restrict__ od, int* __restrict__ id, int ne) {
    int r = blockIdx.y;
    int e = blockIdx.x * 256 + threadIdx.x;
    if (e < ne) {
        atomicAdd(&od[r * 100000 + P.s[r][e]], 1);
        atomicAdd(&id[r * 100000 + P.d[r][e]], 1);
    }
}

// ---------------- combined counts + scan-free segment starts ----------------
__global__ __launch_bounds__(256) void k_cnt(const int* __restrict__ id1, const int* __restrict__ id2,
                                             const int* __restrict__ id3,
                                             int* __restrict__ cnt, int* __restrict__ start,
                                             int* __restrict__ cur, int* cursor, int n) {
    int i = blockIdx.x * 256 + threadIdx.x;
    int c = 0;
    if (i < n) {
        c = id1[i] + id2[i] + id3[i];
        cnt[i] = c;
        cur[i] = 0;
    }
    int lane = threadIdx.x & 63;
    int v = c;
    #pragma unroll
    for (int off = 1; off < 64; off <<= 1) {
        int u = __shfl_up(v, off, 64);
        if (lane >= off) v += u;
    }
    int total = __shfl(v, 63, 64);
    int base = 0;
    if (lane == 63) base = atomicAdd(cursor, total);
    base = __shfl(base, 63, 64);
    if (i < n) start[i] = base + v - c;
}

// ---------------- bucket edges by dst (3 relations in one launch) ----------------
__global__ __launch_bounds__(256) void k_fill3(FillArgs P,
                                               const int* __restrict__ start, int* cur,
                                               int2* __restrict__ e2, int ne) {
    int j = blockIdx.y;
    int e = blockIdx.x * 256 + threadIdx.x;
    if (e >= ne) return;
    int s = P.src[j][e], d = P.dst[j][e];
    int pos = start[d] + atomicAdd(&cur[d], 1);
    int odv = P.od[j][s]; if (odv < 1) odv = 1;
    int idv = P.id[j][d]; if (idv < 1) idv = 1;
    float c = P.w[j][e] * rsqrtf((float)odv) * rsqrtf((float)idv);
    int2 rec; rec.x = P.soff[j] + s; rec.y = __float_as_int(c);
    e2[pos] = rec;
}

// ---------------- fused per-phase GEMM: Z = Xb @ W(region)  ----------------
// 1D grid 7512 = 1252 mblocks x 6 nblocks, n-fastest, XCD-chunked (bijective, 7512%8==0).
// m-blocks padded per src-type region so no block crosses a region boundary.
__global__ __launch_bounds__(256) void k_gemmf(const unsigned short* __restrict__ A,
                                               const unsigned short* __restrict__ WtP,
                                               unsigned short* __restrict__ Z) {
    __shared__ __align__(16) unsigned short As[128 * 32];
    __shared__ __align__(16) unsigned short Bs[128 * 32];
    const int bid = blockIdx.x;
    const int s = (bid & 7) * 939 + (bid >> 3);   // XCD-chunk swizzle (nwg=7512, q=939, r=0)
    const int mb = s / 6;
    const int n0 = (s - mb * 6) * 128;
    int row0, rend, slot;
    if (mb < 782)        { row0 = mb * 128;                  rend = 100000; slot = 0; }
    else if (mb < 1095)  { row0 = 100000 + (mb - 782) * 128; rend = 140000; slot = 1; }
    else                 { row0 = 140000 + (mb - 1095) * 128; rend = 160000; slot = 2; }
    const unsigned short* Bt = WtP + (size_t)slot * 589824;

    const int tid = threadIdx.x;
    const int lane = tid & 63;
    const int wave = tid >> 6;
    const int wm = (wave >> 1) * 64;
    const int wn = (wave & 1) * 64;
    const int l16 = lane & 15;
    const int quad = lane >> 4;

    floatx4 acc[4][4];
    #pragma unroll
    for (int i = 0; i < 4; i++)
        #pragma unroll
        for (int j = 0; j < 4; j++) acc[i][j] = (floatx4){0.f, 0.f, 0.f, 0.f};

    const int l0 = tid;
    const int l1 = tid + 256;
    const int r0 = l0 >> 2, c0 = (l0 & 3) * 8;
    const int r1 = l1 >> 2, c1 = (l1 & 3) * 8;
    int ar0 = row0 + r0; if (ar0 >= rend) ar0 = rend - 1;   // clamp within region
    int ar1 = row0 + r1; if (ar1 >= rend) ar1 = rend - 1;
    const unsigned short* Ag0 = A + (size_t)ar0 * 768 + c0;
    const unsigned short* Ag1 = A + (size_t)ar1 * 768 + c1;
    const unsigned short* Bg0 = Bt + (size_t)(n0 + r0) * 768 + c0;
    const unsigned short* Bg1 = Bt + (size_t)(n0 + r1) * 768 + c1;
    unsigned short* Al0 = As + wave * 512;
    unsigned short* Al1 = As + wave * 512 + 2048;
    unsigned short* Bl0 = Bs + wave * 512;
    unsigned short* Bl1 = Bs + wave * 512 + 2048;

    for (int k0 = 0; k0 < 768; k0 += 32) {
        __syncthreads();
        gload16(Ag0 + k0, Al0);
        gload16(Ag1 + k0, Al1);
        gload16(Bg0 + k0, Bl0);
        gload16(Bg1 + k0, Bl1);
        asm volatile("s_waitcnt vmcnt(0)" ::: "memory");
        __syncthreads();

        short8 af[4], bfr[4];
        #pragma unroll
        for (int mt = 0; mt < 4; mt++)
            af[mt] = *(const short8*)&As[(wm + mt * 16 + l16) * 32 + quad * 8];
        #pragma unroll
        for (int nt = 0; nt < 4; nt++)
            bfr[nt] = *(const short8*)&Bs[(wn + nt * 16 + l16) * 32 + quad * 8];
        #pragma unroll
        for (int mt = 0; mt < 4; mt++)
            #pragma unroll
            for (int nt = 0; nt < 4; nt++)
                acc[mt][nt] = __builtin_amdgcn_mfma_f32_16x16x32_bf16(af[mt], bfr[nt], acc[mt][nt], 0, 0, 0);
    }

    #pragma unroll
    for (int mt = 0; mt < 4; mt++) {
        #pragma unroll
        for (int nt = 0; nt < 4; nt++) {
            const int gr0 = row0 + wm + mt * 16 + quad * 4;
            const int gc = n0 + wn + nt * 16 + l16;
            #pragma unroll
            for (int r = 0; r < 4; r++) {
                int gr = gr0 + r;
                if (gr < rend)
                    Z[(size_t)gr * 768 + gc] = f2bf(acc[mt][nt][r]);
            }
        }
    }
}

// ---------------- dst-centric aggregation + bias + ReLU ----------------
__global__ __launch_bounds__(192) void k_agg(const unsigned short* __restrict__ Z,
                                             const int* __restrict__ start, const int* __restrict__ cnt,
                                             const int2* __restrict__ e2,
                                             const float* __restrict__ b1, const float* __restrict__ b2,
                                             const float* __restrict__ b3,
                                             float* __restrict__ out, int n) {
    int node = blockIdx.x;
    if (node >= n) return;
    int t = threadIdx.x;       // 0..191, owns 4 consecutive cols
    int c0 = t * 4;
    int s = start[node];
    int e = s + cnt[node];
    float ax = 0.f, ay = 0.f, az = 0.f, aw = 0.f;
    for (int i = s; i < e; i++) {
        int2 ed = e2[i];
        float c = __int_as_float(ed.y);
        ushort4 v = *(const ushort4*)(Z + (size_t)ed.x * 768 + c0);
        ax += c * bf2f(v.x);
        ay += c * bf2f(v.y);
        az += c * bf2f(v.z);
        aw += c * bf2f(v.w);
    }
    float4 o;
    o.x = ax + b1[c0 + 0] + b2[c0 + 0] + b3[c0 + 0];
    o.y = ay + b1[c0 + 1] + b2[c0 + 1] + b3[c0 + 1];
    o.z = az + b1[c0 + 2] + b2[c0 + 2] + b3[c0 + 2];
    o.w = aw + b1[c0 + 3] + b2[c0 + 3] + b3[c0 + 3];
    o.x = fmaxf(o.x, 0.f); o.y = fmaxf(o.y, 0.f);
    o.z = fmaxf(o.z, 0.f); o.w = fmaxf(o.w, 0.f);
    *(float4*)(out + (size_t)node * 768 + c0) = o;
}

extern "C" void kernel_launch(void* const* d_in, const int* in_sizes, int n_in,
                              void* d_out, int out_size, void* d_ws, size_t ws_size,
                              hipStream_t stream) {
    const int NM = 100000, NE = 40000, NS = 20000;
    const int EREL = 250000;
    (void)in_sizes; (void)n_in; (void)out_size;

    const float* xM = (const float*)d_in[0];
    const float* xE = (const float*)d_in[1];
    const float* xS = (const float*)d_in[2];
    const int* src[9]; const int* dst[9];
    const float* w[9]; const float* W[9]; const float* b[9];
    for (int r = 0; r < 9; r++) {
        src[r] = (const int*)d_in[3 + 5 * r + 0];
        dst[r] = (const int*)d_in[3 + 5 * r + 1];
        w[r]   = (const float*)d_in[3 + 5 * r + 2];
        W[r]   = (const float*)d_in[3 + 5 * r + 3];
        b[r]   = (const float*)d_in[3 + 5 * r + 4];
    }

    // workspace layout (bytes)
    const size_t XB_OFF = 0;                      // 160000*768 bf16
    const size_t Z_OFF  = 245760000;              // 160000*768 bf16
    const size_t WT_OFF = 491520000;              // 9*768*768 bf16 (slot-ordered [phase][srctype])
    const size_t OD_OFF = 502136832;              // 9*100000 int
    const size_t ID_OFF = 505736832;              // 9*100000 int
    const size_t CURSOR_OFF = 509336832;          // 64 ints (3 used)
    const size_t CNT_OFF = 509337088;              // 100000 int
    const size_t START_OFF = 509737088;           // 100000 int
    const size_t CUR_OFF = 510137088;             // 100000 int
    const size_t E2_OFF = 510537088;              // 750000 int2
    const size_t WS_NEEDED = 516537088;
    if (ws_size < WS_NEEDED) return;

    char* ws = (char*)d_ws;
    unsigned short* Xb = (unsigned short*)(ws + XB_OFF);
    unsigned short* Z  = (unsigned short*)(ws + Z_OFF);
    unsigned short* Wt = (unsigned short*)(ws + WT_OFF);
    int* od     = (int*)(ws + OD_OFF);
    int* id     = (int*)(ws + ID_OFF);
    int* cursor = (int*)(ws + CURSOR_OFF);
    int* cnt    = (int*)(ws + CNT_OFF);
    int* start  = (int*)(ws + START_OFF);
    int* cur    = (int*)(ws + CUR_OFF);
    int2* e2    = (int2*)(ws + E2_OFF);

    // RELS = M_M,M_E,M_S,E_S,E_M,S_M,S_E,S_S,E_E
    const int rel_soff[9] = {0, 0, 0, 100000, 100000, 140000, 140000, 140000, 100000};
    // Wt slot = phase*3 + srctype  (src: M=0,E=1,S=2; phase = dst type M/E/S)
    const int wtslot[9] = {0, 3, 6, 7, 1, 2, 5, 8, 4};
    const int phase_nd[3]  = {NM, NE, NS};
    const int phase_out[3] = {0, 100000, 140000};
    const int phase_rels[3][3] = { {0, 4, 5}, {1, 8, 6}, {2, 3, 7} };  // dst M / E / S

    // zero od+id+cursor block
    k_zero<<<1760, 256, 0, stream>>>(od, 1800064);

    const int eblk = (EREL + 255) / 256;
    DegArgs dp;
    for (int r = 0; r < 9; r++) { dp.s[r] = src[r]; dp.d[r] = dst[r]; }
    k_deg_all<<<dim3(eblk, 9), 256, 0, stream>>>(dp, od, id, EREL);

    CvtArgs cp; cp.xM = xM; cp.xE = xE; cp.xS = xS;
    k_cvt_all<<<4096, 256, 0, stream>>>(cp, Xb);

    TwtArgs tp;
    for (int r = 0; r < 9; r++) { tp.W[r] = W[r]; tp.slot[r] = wtslot[r]; }
    k_twt_all<<<dim3(24, 24, 9), dim3(32, 8), 0, stream>>>(tp, Wt);

    for (int p = 0; p < 3; p++) {
        const int nd = phase_nd[p];
        const int r0 = phase_rels[p][0], r1 = phase_rels[p][1], r2 = phase_rels[p][2];

        // one fused GEMM covering all 160000 rows, region-selected Wt
        k_gemmf<<<7512, 256, 0, stream>>>(Xb, Wt + (size_t)p * 3 * 589824, Z);

        k_cnt<<<(nd + 255) / 256, 256, 0, stream>>>(id + r0 * 100000, id + r1 * 100000,
                                                    id + r2 * 100000, cnt, start, cur, cursor + p, nd);
        FillArgs fp;
        for (int j = 0; j < 3; j++) {
            int r = phase_rels[p][j];
            fp.src[j] = src[r]; fp.dst[j] = dst[r]; fp.w[j] = w[r];
            fp.od[j] = od + r * 100000; fp.id[j] = id + r * 100000;
            fp.soff[j] = rel_soff[r];
        }
        k_fill3<<<dim3(eblk, 3), 256, 0, stream>>>(fp, start, cur, e2, EREL);

        k_agg<<<nd, 192, 0, stream>>>(Z, start, cnt, e2, b[r0], b[r1], b[r2],
                                      (float*)d_out + (size_t)phase_out[p] * 768, nd);
    }
}